// Round 1
// baseline (6056.023 us; speedup 1.0000x reference)
//
#include <hip/hip_runtime.h>
#include <math.h>

// Problem constants
#define B_    512
#define T_    256
#define DIN   64
#define DS    64
#define KK    128   // DIN + DS
#define NN    2048
#define DOUT  10

// Tiling
#define BT      32              // batch rows per WG
#define NT      128             // neurons per WG
#define BTILES  (B_ / BT)       // 16
#define NTILES  (NN / NT)       // 16
#define THREADS 512

// Partial-state buffer: [2][NTILES][B_][DS] floats  (2 x 2MB in d_ws)
#define PS_ELEMS ((size_t)NTILES * B_ * DS)

__global__ __launch_bounds__(256) void init_kernel(float* __restrict__ ps0,
                                                   float* __restrict__ out) {
    size_t i = (size_t)blockIdx.x * blockDim.x + threadIdx.x;
    size_t stride = (size_t)gridDim.x * blockDim.x;
    for (size_t k = i; k < PS_ELEMS; k += stride) ps0[k] = 0.0f;
    for (size_t k = i; k < (size_t)B_ * DOUT; k += stride) out[k] = 0.0f;
}

__global__ __launch_bounds__(THREADS) void step_kernel(
    const float* __restrict__ seq,   // [B][T][DIN]
    const float* __restrict__ enc,   // [NN][KK]
    const float* __restrict__ bias,  // [NN]
    const float* __restrict__ gain,  // [NN]
    const float* __restrict__ sd,    // [NN][DS]
    const float* __restrict__ dec,   // [NN][DOUT]
    const float* __restrict__ ps_r,  // [NTILES][B_][DS]
    float* __restrict__ ps_w,        // [NTILES][B_][DS]
    float* __restrict__ out,         // [B_][DOUT]
    int t, int last)
{
    __shared__ float xs[BT][KK];      // 32*128*4 = 16 KB, x_aug tile
    __shared__ float As[NT][BT + 4];  // 128*36*4 = 18.4 KB, activation tile, [n][r], 16B-aligned rows

    const int tid = threadIdx.x;
    const int nt_idx = blockIdx.x % NTILES;
    const int bt_idx = blockIdx.x / NTILES;
    const int n0 = nt_idx * NT;
    const int b0 = bt_idx * BT;

    // ---- stage x_aug = [u_t | sum_nt PS] into LDS ----
    {
        const int r = tid / 16;            // 0..31
        const int c = (tid % 16) * 4;      // 0..60
        // input part: seq[b0+r][t][c..c+3]
        const float4 uv = *(const float4*)&seq[((size_t)(b0 + r) * T_ + t) * DIN + c];
        *(float4*)&xs[r][c] = uv;
        // state part: reduce the 16 neuron-tile partials
        float4 acc = {0.f, 0.f, 0.f, 0.f};
        #pragma unroll
        for (int nt = 0; nt < NTILES; ++nt) {
            const float4 v = *(const float4*)&ps_r[((size_t)nt * B_ + b0 + r) * DS + c];
            acc.x += v.x; acc.y += v.y; acc.z += v.z; acc.w += v.w;
        }
        *(float4*)&xs[r][DIN + c] = acc;
    }
    __syncthreads();

    // ---- encode: A[32 rows][128 neurons] = |gain * (xs @ E^T) + bias| ----
    // thread tile: 2 neurons (ng, ng+64) x 4 rows (rg*4 .. rg*4+3)
    const int ng = tid & 63;   // wave-aligned: a wave shares rg -> xs reads broadcast
    const int rg = tid >> 6;   // 0..7
    float acc[2][4];
    #pragma unroll
    for (int i = 0; i < 2; ++i)
        #pragma unroll
        for (int j = 0; j < 4; ++j) acc[i][j] = 0.f;

    const float* e0 = &enc[(size_t)(n0 + ng) * KK];
    const float* e1 = &enc[(size_t)(n0 + ng + 64) * KK];
    #pragma unroll 4
    for (int k = 0; k < KK; k += 4) {
        const float4 ev0 = *(const float4*)&e0[k];
        const float4 ev1 = *(const float4*)&e1[k];
        #pragma unroll
        for (int j = 0; j < 4; ++j) {
            const float4 xv = *(const float4*)&xs[rg * 4 + j][k];
            acc[0][j] += ev0.x * xv.x + ev0.y * xv.y + ev0.z * xv.z + ev0.w * xv.w;
            acc[1][j] += ev1.x * xv.x + ev1.y * xv.y + ev1.z * xv.z + ev1.w * xv.w;
        }
    }

    #pragma unroll
    for (int i = 0; i < 2; ++i) {
        const int n = n0 + ng + 64 * i;
        const float g = gain[n];
        const float bb = bias[n];
        float4 av;
        av.x = fabsf(g * acc[i][0] + bb);
        av.y = fabsf(g * acc[i][1] + bb);
        av.z = fabsf(g * acc[i][2] + bb);
        av.w = fabsf(g * acc[i][3] + bb);
        *(float4*)&As[ng + 64 * i][rg * 4] = av;
    }
    __syncthreads();

    if (!last) {
        // ---- decode partial: PS[nt][b0+r][j] = sum_{n in tile} A[r][n] * SD[n][j] ----
        // thread: column j (0..63), 4 rows r0..r0+3
        const int j = tid & 63;
        const int r0 = (tid >> 6) * 4;
        float s0 = 0.f, s1 = 0.f, s2 = 0.f, s3 = 0.f;
        #pragma unroll 8
        for (int nl = 0; nl < NT; ++nl) {
            const float sv = sd[(size_t)(n0 + nl) * DS + j];      // coalesced, L2-hot
            const float4 av = *(const float4*)&As[nl][r0];        // wave broadcast
            s0 += av.x * sv; s1 += av.y * sv; s2 += av.z * sv; s3 += av.w * sv;
        }
        ps_w[((size_t)nt_idx * B_ + b0 + r0 + 0) * DS + j] = s0;
        ps_w[((size_t)nt_idx * B_ + b0 + r0 + 1) * DS + j] = s1;
        ps_w[((size_t)nt_idx * B_ + b0 + r0 + 2) * DS + j] = s2;
        ps_w[((size_t)nt_idx * B_ + b0 + r0 + 3) * DS + j] = s3;
    } else {
        // ---- final projection: out[b][d] += sum_{n in tile} A[r][n] * dec[n][d] ----
        for (int idx = tid; idx < BT * DOUT; idx += THREADS) {
            const int r = idx / DOUT;
            const int d = idx % DOUT;
            float o = 0.f;
            #pragma unroll 8
            for (int nl = 0; nl < NT; ++nl)
                o += As[nl][r] * dec[(size_t)(n0 + nl) * DOUT + d];
            atomicAdd(&out[(size_t)(b0 + r) * DOUT + d], o);
        }
    }
}

extern "C" void kernel_launch(void* const* d_in, const int* in_sizes, int n_in,
                              void* d_out, int out_size, void* d_ws, size_t ws_size,
                              hipStream_t stream) {
    const float* seq  = (const float*)d_in[0];
    const float* enc  = (const float*)d_in[1];
    const float* bias = (const float*)d_in[2];
    const float* gain = (const float*)d_in[3];
    const float* sd   = (const float*)d_in[4];
    const float* dec  = (const float*)d_in[5];
    float* out = (float*)d_out;
    float* ps  = (float*)d_ws;  // [2][NTILES][B_][DS] floats = 4 MB

    init_kernel<<<dim3(512), dim3(256), 0, stream>>>(ps, out);

    for (int t = 0; t < T_; ++t) {
        const float* ps_r = ps + (size_t)(t & 1) * PS_ELEMS;
        float*       ps_w = ps + (size_t)((t + 1) & 1) * PS_ELEMS;
        step_kernel<<<dim3(BTILES * NTILES), dim3(THREADS), 0, stream>>>(
            seq, enc, bias, gain, sd, dec, ps_r, ps_w, out, t, (t == T_ - 1) ? 1 : 0);
    }
}

// Round 2
// 5745.874 us; speedup vs baseline: 1.0540x; 1.0540x over previous
//
#include <hip/hip_runtime.h>
#include <math.h>

// Problem constants
#define B_    512
#define T_    256
#define DIN   64
#define DS    64
#define KK    128   // DIN + DS
#define NN    2048
#define DOUT  10

// Tiling: grid = NTILES x BTILES = 16 x 32 = 512 WGs (2/CU), 256 thr (4 waves)
#define NT      128
#define BT      16
#define NTILES  (NN / NT)    // 16
#define BTILES  (B_ / BT)    // 32
#define THREADS 256

// Workspace layout (floats): ps ping/pong then transposed encoders Et[KK][NN]
#define PS_ELEMS ((size_t)NTILES * B_ * DS)   // 524288
#define ET_OFF   (2 * PS_ELEMS)
#define ET_ELEMS ((size_t)KK * NN)            // 262144

__global__ __launch_bounds__(256) void pre_kernel(const float* __restrict__ enc,
                                                  float* __restrict__ ws,
                                                  float* __restrict__ out) {
    size_t i = (size_t)blockIdx.x * blockDim.x + threadIdx.x;
    size_t stride = (size_t)gridDim.x * blockDim.x;
    for (size_t x = i; x < PS_ELEMS; x += stride) ws[x] = 0.0f;   // zero ping buffer
    for (size_t x = i; x < ET_ELEMS; x += stride) {               // Et[k][n] = enc[n][k]
        int k = (int)(x >> 11);      // / 2048
        int n = (int)(x & 2047);
        ws[ET_OFF + x] = enc[(size_t)n * KK + k];
    }
    for (size_t x = i; x < (size_t)B_ * DOUT; x += stride) out[x] = 0.0f;
}

__global__ __launch_bounds__(THREADS) void step_kernel(
    const float* __restrict__ seq,   // [B][T][DIN]
    const float* __restrict__ Et,    // [KK][NN] transposed encoders
    const float* __restrict__ bias,  // [NN]
    const float* __restrict__ gain,  // [NN]
    const float* __restrict__ sd,    // [NN][DS]
    const float* __restrict__ dec,   // [NN][DOUT]
    const float* __restrict__ ps_r,  // [NTILES][B_][DS]
    float* __restrict__ ps_w,        // [NTILES][B_][DS]
    float* __restrict__ out,         // [B_][DOUT]
    int t, int last)
{
    __shared__ float xs[BT][132];    // x_aug tile, row-major, pad 132 (diag banks)
    __shared__ float As[BT][132];    // activations, [row][neuron], b128-aligned
    __shared__ float Ap[NT][17];     // kw=1 partials, stride 17 (<=4-way conflicts)

    const int tid = threadIdx.x;
    const int nt = blockIdx.x & (NTILES - 1);
    const int bt = blockIdx.x >> 4;
    const int n0 = nt * NT;
    const int b0 = bt * BT;

    // ---- phase 1: build x_aug = [u_t | sum_nt PS] in LDS ----
    {
        const int r = tid >> 4;            // 0..15
        const int c = (tid & 15) << 2;     // 0..60
        const float4 uv = *(const float4*)&seq[((size_t)(b0 + r) * T_ + t) * DIN + c];
        *(float4*)&xs[r][c] = uv;
        float4 a = {0.f, 0.f, 0.f, 0.f};
        #pragma unroll
        for (int p = 0; p < NTILES; ++p) {
            const float4 v = *(const float4*)&ps_r[((size_t)p * B_ + b0 + r) * DS + c];
            a.x += v.x; a.y += v.y; a.z += v.z; a.w += v.w;
        }
        *(float4*)&xs[r][DIN + c] = a;
    }
    __syncthreads();

    // ---- phase 2: encode, k-split ----
    // wave w: rw=w&1 (8 rows), kw=w>>1 (64 k); half h=l>>5 (32 k); lane q: neurons 4q..4q+3
    const int w   = tid >> 6;
    const int l   = tid & 63;
    const int rw  = w & 1;
    const int kw  = w >> 1;
    const int h   = l >> 5;
    const int q   = l & 31;
    const int k0  = kw * 64 + h * 32;
    const int r0e = rw * 8;

    float4 acc[8];
    #pragma unroll
    for (int r = 0; r < 8; ++r) { acc[r].x = 0.f; acc[r].y = 0.f; acc[r].z = 0.f; acc[r].w = 0.f; }

    #pragma unroll
    for (int b = 0; b < 8; ++b) {
        const int kb = k0 + b * 4;
        const float* ep = &Et[(size_t)kb * NN + n0 + 4 * q];
        const float4 e0 = *(const float4*)(ep);
        const float4 e1 = *(const float4*)(ep + NN);
        const float4 e2 = *(const float4*)(ep + 2 * (size_t)NN);
        const float4 e3 = *(const float4*)(ep + 3 * (size_t)NN);
        #pragma unroll
        for (int r = 0; r < 8; ++r) {
            const float4 xv = *(const float4*)&xs[r0e + r][kb];
            acc[r].x += e0.x * xv.x + e1.x * xv.y + e2.x * xv.z + e3.x * xv.w;
            acc[r].y += e0.y * xv.x + e1.y * xv.y + e2.y * xv.z + e3.y * xv.w;
            acc[r].z += e0.z * xv.x + e1.z * xv.y + e2.z * xv.z + e3.z * xv.w;
            acc[r].w += e0.w * xv.x + e1.w * xv.y + e2.w * xv.z + e3.w * xv.w;
        }
    }

    // reduce the two half-wave k-slices in-register
    #pragma unroll
    for (int r = 0; r < 8; ++r) {
        acc[r].x += __shfl_xor(acc[r].x, 32);
        acc[r].y += __shfl_xor(acc[r].y, 32);
        acc[r].z += __shfl_xor(acc[r].z, 32);
        acc[r].w += __shfl_xor(acc[r].w, 32);
    }

    // cross-wave (kw) reduce via LDS; kw=1 h=0 lanes publish
    if (w >= 2 && h == 0) {
        #pragma unroll
        for (int r = 0; r < 8; ++r) {
            Ap[4 * q + 0][r0e + r] = acc[r].x;
            Ap[4 * q + 1][r0e + r] = acc[r].y;
            Ap[4 * q + 2][r0e + r] = acc[r].z;
            Ap[4 * q + 3][r0e + r] = acc[r].w;
        }
    }
    __syncthreads();

    if (w < 2 && h == 0) {
        const float4 g4 = *(const float4*)&gain[n0 + 4 * q];
        const float4 b4 = *(const float4*)&bias[n0 + 4 * q];
        #pragma unroll
        for (int r = 0; r < 8; ++r) {
            float4 v = acc[r];
            v.x += Ap[4 * q + 0][r0e + r];
            v.y += Ap[4 * q + 1][r0e + r];
            v.z += Ap[4 * q + 2][r0e + r];
            v.w += Ap[4 * q + 3][r0e + r];
            float4 a;
            a.x = fabsf(g4.x * v.x + b4.x);
            a.y = fabsf(g4.y * v.y + b4.y);
            a.z = fabsf(g4.z * v.z + b4.z);
            a.w = fabsf(g4.w * v.w + b4.w);
            *(float4*)&As[r0e + r][4 * q] = a;
        }
    }
    __syncthreads();

    if (!last) {
        // ---- phase 3: decode. lane -> (4 state cols, 1 row); full 128-neuron sum ----
        const int jg  = (l & 15) << 2;       // state col group
        const int rgd = w * 4 + (l >> 4);    // row 0..15
        float4 s = {0.f, 0.f, 0.f, 0.f};
        #pragma unroll 8
        for (int nb = 0; nb < 32; ++nb) {
            const float4 av = *(const float4*)&As[rgd][nb * 4];
            const float* sp = &sd[(size_t)(n0 + nb * 4) * DS + jg];
            const float4 s0 = *(const float4*)(sp);
            const float4 s1 = *(const float4*)(sp + DS);
            const float4 s2 = *(const float4*)(sp + 2 * DS);
            const float4 s3 = *(const float4*)(sp + 3 * DS);
            s.x += av.x * s0.x + av.y * s1.x + av.z * s2.x + av.w * s3.x;
            s.y += av.x * s0.y + av.y * s1.y + av.z * s2.y + av.w * s3.y;
            s.z += av.x * s0.z + av.y * s1.z + av.z * s2.z + av.w * s3.z;
            s.w += av.x * s0.w + av.y * s1.w + av.z * s2.w + av.w * s3.w;
        }
        *(float4*)&ps_w[((size_t)nt * B_ + b0 + rgd) * DS + jg] = s;
    } else {
        // ---- final projection: out += A_tile @ dec_tile ----
        for (int idx = tid; idx < BT * DOUT; idx += THREADS) {
            const int r = idx / DOUT;
            const int d = idx % DOUT;
            float o = 0.f;
            #pragma unroll 8
            for (int n = 0; n < NT; ++n)
                o += As[r][n] * dec[(size_t)(n0 + n) * DOUT + d];
            atomicAdd(&out[(size_t)(b0 + r) * DOUT + d], o);
        }
    }
}

extern "C" void kernel_launch(void* const* d_in, const int* in_sizes, int n_in,
                              void* d_out, int out_size, void* d_ws, size_t ws_size,
                              hipStream_t stream) {
    const float* seq  = (const float*)d_in[0];
    const float* enc  = (const float*)d_in[1];
    const float* bias = (const float*)d_in[2];
    const float* gain = (const float*)d_in[3];
    const float* sd   = (const float*)d_in[4];
    const float* dec  = (const float*)d_in[5];
    float* out = (float*)d_out;
    float* ws  = (float*)d_ws;            // [2][PS_ELEMS] ps + Et (5 MB total)
    const float* Et = ws + ET_OFF;

    pre_kernel<<<dim3(1024), dim3(256), 0, stream>>>(enc, ws, out);

    for (int t = 0; t < T_; ++t) {
        const float* ps_r = ws + (size_t)(t & 1) * PS_ELEMS;
        float*       ps_w = ws + (size_t)((t + 1) & 1) * PS_ELEMS;
        step_kernel<<<dim3(NTILES * BTILES), dim3(THREADS), 0, stream>>>(
            seq, Et, bias, gain, sd, dec, ps_r, ps_w, out, t, (t == T_ - 1) ? 1 : 0);
    }
}